// Round 8
// baseline (210.808 us; speedup 1.0000x reference)
//
#include <hip/hip_runtime.h>

// 2D gated linear recurrence, scanned over width.
// H[b,c,h,w] = B*X + G1*H[h-1,w-1] + G2*H[h,w-1] + G3*H[h+1,w-1]
// [16,32,128,128] fp32, w innermost.
//
// v4b: same as v4 (TLP doubling: one plane per 128-thread block, 2 waves,
// cooperative staging, padded transposed LDS, per-step mailbox+barrier),
// with the compile fix: nontemporal builtins need a true vector type,
// so use ext_vector_type(4) float instead of HIP float4.

constexpr int HGT = 128;
constexpr int WID = 128;
constexpr int PLANES = 16 * 32;   // 512
constexpr int WT = 16;            // w-columns per tile (64 B per row)
constexpr int NT = WID / WT;      // 8 tiles
constexpr int S  = 132;           // padded transposed h-stride (dwords)
constexpr int ASZ = WT * S;       // 2112 dwords per array slab

typedef float f32x4 __attribute__((ext_vector_type(4)));

__global__ __launch_bounds__(128, 1) void spn2d_kernel(
    const float* __restrict__ Xp, const float* __restrict__ Bp,
    const float* __restrict__ G1p, const float* __restrict__ G2p,
    const float* __restrict__ G3p, float* __restrict__ Op)
{
    __shared__ float lds[6 * ASZ];  // 5 input slabs + 1 output slab = 50688 B
    __shared__ float mb[4];         // mailbox: H[63] parity {0,1}, H[64] parity {0,1}

    const int tid = threadIdx.x;    // 0..127
    const int wv  = tid >> 6;       // wave id: 0 -> rows 0..63, 1 -> rows 64..127
    const int l   = tid & 63;       // lane
    const int plane = blockIdx.x;
    const size_t pbase = (size_t)plane * HGT * WID;

    const float* __restrict__ src[5] = {Xp, Bp, G1p, G2p, G3p};

    // Cooperative staging geometry (128 threads):
    //   instr i in 0..3: row h = 32*i + (tid>>2), w-seg = 4*(tid&3)
    //   4 adjacent threads cover one full 64B row segment.
    const int rq  = tid >> 2;       // 0..31
    const int ws4 = (tid & 3) * 4;  // 0,4,8,12

    f32x4 bufA[20], bufB[20];

    auto load_tile = [&](int t, f32x4 (&buf)[20]) {
        #pragma unroll
        for (int a = 0; a < 5; ++a) {
            const float* p = src[a] + pbase + (size_t)t * WT + ws4;
            #pragma unroll
            for (int i = 0; i < 4; ++i) {
                buf[a * 4 + i] = __builtin_nontemporal_load(
                    (const f32x4*)(p + (size_t)(32 * i + rq) * WID));
            }
        }
    };

    auto stage_tile = [&](f32x4 (&buf)[20]) {
        #pragma unroll
        for (int a = 0; a < 5; ++a) {
            #pragma unroll
            for (int i = 0; i < 4; ++i) {
                const int h = 32 * i + rq;
                f32x4 v = buf[a * 4 + i];
                // bank = (4*(ws4+j) + h) % 32 -> exactly 2 lanes/bank (free)
                lds[a * ASZ + (ws4 + 0) * S + h] = v.x;
                lds[a * ASZ + (ws4 + 1) * S + h] = v.y;
                lds[a * ASZ + (ws4 + 2) * S + h] = v.z;
                lds[a * ASZ + (ws4 + 3) * S + h] = v.w;
            }
        }
    };

    float h = 0.f;                  // recurrence carry for row 64*wv + l
    const int row = 64 * wv + l;

    auto compute_tile = [&]() {
        #pragma unroll
        for (int w = 0; w < WT; ++w) {
            const int off = w * S + row;           // bank = (4w + l) % 32: 2-way
            const float xv = lds[0 * ASZ + off];
            const float bv = lds[1 * ASZ + off];
            const float g1 = lds[2 * ASZ + off];
            const float g2 = lds[3 * ASZ + off];
            const float g3 = lds[4 * ASZ + off];

            float up = __shfl_up(h, 1, 64);        // H[row-1, w-1] within wave
            float dn = __shfl_down(h, 1, 64);      // H[row+1, w-1] within wave
            if (l == 0)  up = (wv == 0) ? 0.f : mb[w & 1];        // H[63,w-1]
            if (l == 63) dn = (wv == 1) ? 0.f : mb[2 + (w & 1)];  // H[64,w-1]

            h = bv * xv + g1 * up + g2 * h + g3 * dn;
            lds[5 * ASZ + off] = h;

            if (wv == 0 && l == 63) mb[(w & 1) ^ 1]       = h;  // new H[63,w]
            if (wv == 1 && l == 0)  mb[2 + ((w & 1) ^ 1)] = h;  // new H[64,w]
            __syncthreads();   // mailbox + out-slab visibility, step ordering
        }
    };

    auto out_stage = [&](int t) {
        float* o = Op + pbase + (size_t)t * WT + ws4;
        #pragma unroll
        for (int i = 0; i < 4; ++i) {
            const int hh = 32 * i + rq;
            f32x4 v;
            v.x = lds[5 * ASZ + (ws4 + 0) * S + hh];
            v.y = lds[5 * ASZ + (ws4 + 1) * S + hh];
            v.z = lds[5 * ASZ + (ws4 + 2) * S + hh];
            v.w = lds[5 * ASZ + (ws4 + 3) * S + hh];
            __builtin_nontemporal_store(v, (f32x4*)(o + (size_t)hh * WID));
        }
    };

    auto tile_body = [&](int t, f32x4 (&cur)[20], f32x4 (&nxt)[20]) {
        if (t + 1 < NT) load_tile(t + 1, nxt);  // prefetch next tile (VMEM issue)
        stage_tile(cur);                        // vmcnt wait + LDS transpose
        __syncthreads();                        // stage visible to both waves
        compute_tile();                         // 16 steps, barrier each
        out_stage(t);                           // transposed read + NT store
        __syncthreads();                        // out-reads done before reuse
    };

    // mailbox init: step 0 reads parity-0 slots, must be zero
    if (tid < 4) mb[tid] = 0.f;
    load_tile(0, bufA);
    __syncthreads();

    for (int t = 0; t < NT; t += 2) {
        tile_body(t,     bufA, bufB);
        tile_body(t + 1, bufB, bufA);
    }
}

extern "C" void kernel_launch(void* const* d_in, const int* in_sizes, int n_in,
                              void* d_out, int out_size, void* d_ws, size_t ws_size,
                              hipStream_t stream) {
    const float* X  = (const float*)d_in[0];
    const float* B  = (const float*)d_in[1];
    const float* G1 = (const float*)d_in[2];
    const float* G2 = (const float*)d_in[3];
    const float* G3 = (const float*)d_in[4];
    float* O = (float*)d_out;

    spn2d_kernel<<<dim3(PLANES), dim3(128), 0, stream>>>(X, B, G1, G2, G3, O);
}